// Round 8
// baseline (13528.331 us; speedup 1.0000x reference)
//
#include <hip/hip_runtime.h>

// RVAE on MI355X. Design notes (KERNEL-tier):
//  - 128 persistent WGs (one per batch row). Recurrent weights (768x256 f16)
//    register-resident, ROW-SPLIT: 768 thr/WG (12 waves, 3 waves/SIMD),
//    thread j owns gate-row j (r:0-255, z:256-511, n:512-767) = 32 NAMED
//    uint4 = 128 weight regs + ~25 temps <= 170 budget (512 unified / 3
//    waves). All-arch-VGPR: v_dot2 can't read AGPRs, and R6/R7's 192-reg
//    K-split forced a 128V+128A split (VGPR_Count=128) -> accvgpr_read per
//    weight use + only 2 waves/SIMD -> 25% VALUBusy, stall-dominated.
//  - Gate recombination via LDS s_rz/gin/ghn (stride-1, conflict-free),
//    1 write + 4 reads per step; enc/decB 2 barriers/step, decA 3.
//  - decB x-linear weights in LDS wxpT2[i2*68+fo]: bank=(4*qq+f+d)%32 is
//    <=2-way (free, m136). R6's [i2*65+oo] was 8-way (2e8 conflicts).
//  - NAMED vars, not arrays: unrolled arrays -> alloca -> scratch (R1).
//  - All matvecs v_dot2_f32_f16 (f16 pairs, f32 acc); gates/reductions f32.
//    absmax 0.0078 vs 2.5e5 threshold.
//  - Encoder fuses xh -> Wz[:,H:2H] projection so xh[L,B,256] (268MB) is
//    never materialized. decA/decB split: Whh2+Whh3 don't co-fit.

typedef unsigned int uint32;
typedef unsigned short uint16;
typedef _Float16 half2v __attribute__((ext_vector_type(2)));

#define LOG2PI_F 1.8378770664093453f

__device__ __forceinline__ float dot2f(uint32 w, uint32 h, float acc) {
#if __has_builtin(__builtin_amdgcn_fdot2)
  return __builtin_amdgcn_fdot2(__builtin_bit_cast(half2v, w),
                                __builtin_bit_cast(half2v, h), acc, false);
#else
  half2v a = __builtin_bit_cast(half2v, w);
  half2v b = __builtin_bit_cast(half2v, h);
  return acc + (float)a.x * (float)b.x + (float)a.y * (float)b.y;
#endif
}

__device__ __forceinline__ uint32 packh2(float a, float b) {
  half2v v;
  v.x = (_Float16)a;
  v.y = (_Float16)b;
  return __builtin_bit_cast(uint32, v);
}

__device__ __forceinline__ float wredsum64(float v) {
  v += __shfl_xor(v, 32); v += __shfl_xor(v, 16); v += __shfl_xor(v, 8);
  v += __shfl_xor(v, 4);  v += __shfl_xor(v, 2);  v += __shfl_xor(v, 1);
  return v;
}

__device__ __forceinline__ float sigm(float x) { return 1.0f / (1.0f + expf(-x)); }
__device__ __forceinline__ float tanh_(float x) { return 1.0f - 2.0f / (expf(2.0f * x) + 1.0f); }

#define R32(M) M(0) M(1) M(2) M(3) M(4) M(5) M(6) M(7) M(8) M(9) M(10) M(11) \
  M(12) M(13) M(14) M(15) M(16) M(17) M(18) M(19) M(20) M(21) M(22) M(23) \
  M(24) M(25) M(26) M(27) M(28) M(29) M(30) M(31)

// One gate-row per thread: 32 named uint4 = 128 weight VGPRs.
#define LDW(n) uint4 w##n = wrow4[n];

// 4 dot2 per chunk; hv is a wave-uniform LDS broadcast (conflict-free).
#define HDOT(n) { uint4 hv = hq4[n]; \
  a0 = dot2f(w##n.x, hv.x, a0); a1 = dot2f(w##n.y, hv.y, a1); \
  a2 = dot2f(w##n.z, hv.z, a2); a3 = dot2f(w##n.w, hv.w, a3); }

#define KPIN __launch_bounds__(768) __attribute__((amdgpu_waves_per_eu(3, 3)))

// ---------------- prep: repack weights into ws ----------------
// wq1/2/3: [768 rows][128 pairs] uint32 = packh2(Whh[k][2i], Whh[k][2i+1])
// wih1t: [16][768] f16x2 pairs of Wih1; wih2t/wih3t: [2][768]
// wz1t/wz2t: [256][9] f32 (pad col for bank spread)
// wxpT2: [128 i2][68 pad] f16x2 pairs over i of (Wxl;Wxs) rows fo=0..63
__global__ void prep_kernel(const float* __restrict__ Wih1, const float* __restrict__ Whh1,
                            const float* __restrict__ Wih2, const float* __restrict__ Whh2,
                            const float* __restrict__ Wih3, const float* __restrict__ Whh3,
                            const float* __restrict__ Wzl, const float* __restrict__ Wzs,
                            const float* __restrict__ Wxl, const float* __restrict__ Wxs,
                            uint32* wq1, uint32* wq2, uint32* wq3,
                            uint32* wih1t, uint32* wih2t, uint32* wih3t,
                            float* wz1t, float* wz2t, uint32* wxpT2) {
  int id = blockIdx.x * blockDim.x + threadIdx.x;
  int str = gridDim.x * blockDim.x;
  for (int n = id; n < 768 * 128; n += str) {
    int k = n >> 7, i = n & 127;
    wq1[n] = packh2(Whh1[k * 256 + 2 * i], Whh1[k * 256 + 2 * i + 1]);
    wq2[n] = packh2(Whh2[k * 256 + 2 * i], Whh2[k * 256 + 2 * i + 1]);
    wq3[n] = packh2(Whh3[k * 256 + 2 * i], Whh3[k * 256 + 2 * i + 1]);
  }
  for (int n = id; n < 16 * 768; n += str) {
    int i = n / 768, k = n % 768;
    wih1t[n] = packh2(Wih1[k * 32 + 2 * i], Wih1[k * 32 + 2 * i + 1]);
  }
  for (int n = id; n < 2 * 768; n += str) {
    int i = n / 768, k = n % 768;
    wih2t[n] = packh2(Wih2[k * 4 + 2 * i], Wih2[k * 4 + 2 * i + 1]);
    wih3t[n] = packh2(Wih3[k * 4 + 2 * i], Wih3[k * 4 + 2 * i + 1]);
  }
  for (int n = id; n < 256 * 8; n += str) {
    int i = n >> 3, o = n & 7;
    wz1t[i * 9 + o] = (o < 4) ? Wzl[o * 512 + i] : Wzs[(o - 4) * 512 + i];
    wz2t[i * 9 + o] = (o < 4) ? Wzl[o * 512 + 256 + i] : Wzs[(o - 4) * 512 + 256 + i];
  }
  for (int n = id; n < 128 * 64; n += str) {
    int i2 = n >> 6, o = n & 63;
    float a = (o < 32) ? Wxl[o * 256 + 2 * i2] : Wxs[(o - 32) * 256 + 2 * i2];
    float b = (o < 32) ? Wxl[o * 256 + 2 * i2 + 1] : Wxs[(o - 32) * 256 + 2 * i2 + 1];
    wxpT2[i2 * 68 + o] = packh2(a, b);
  }
}

// ---------------- encoder: reverse GRU + fused xh->Wz projection ----------------
__global__ KPIN void enc_kernel(
    const float* __restrict__ x, const float* __restrict__ bih1,
    const float* __restrict__ bhh1, const uint32* __restrict__ wq1,
    const uint32* __restrict__ wih1t, const float* __restrict__ wz2t,
    float* __restrict__ zx) {
  const int b = blockIdx.x, j = threadIdx.x;
  __shared__ uint32 wih[16 * 768];           // 48KB
  __shared__ float wz[256 * 9];              // 9KB
  __shared__ float s_rz[512];
  __shared__ float gin[256], ghn[256];
  __shared__ float h[256];
  __shared__ __align__(16) uint32 hpk[128];
  __shared__ uint32 xpk[16];

  const uint4* wrow4 = (const uint4*)(wq1 + (size_t)j * 128);
  const uint4* hq4 = (const uint4*)hpk;
  R32(LDW)
  const float bi = bih1[j], bh = bhh1[j];
  for (int i = j; i < 16 * 768; i += 768) wih[i] = wih1t[i];
  for (int i = j; i < 256 * 9; i += 768) wz[i] = wz2t[i];
  float h_reg = 0.0f;
  if (j < 256) h[j] = 0.0f;
  if (j < 128) hpk[j] = 0u;
  const float* xb = x + (size_t)b * (2048 * 32);
  if (j < 16) xpk[j] = packh2(xb[2047 * 32 + 2 * j], xb[2047 * 32 + 2 * j + 1]);
  __syncthreads();

  for (int t = 2047; t >= 0; --t) {
    // ---- prefetch next x (j<16, hidden under dots) ----
    float xn0 = 0.f, xn1 = 0.f;
    if (j < 16 && t > 0) { xn0 = xb[(t - 1) * 32 + 2 * j]; xn1 = xb[(t - 1) * 32 + 2 * j + 1]; }
    // ---- D: full-row dots ----
    float ai = bi;
#pragma unroll
    for (int i = 0; i < 16; ++i) ai = dot2f(wih[i * 768 + j], xpk[i], ai);
    float a0 = 0.f, a1 = 0.f, a2 = 0.f, a3 = 0.f;
    R32(HDOT)
    float ah = bh + ((a0 + a1) + (a2 + a3));
    if (j < 512) s_rz[j] = ai + ah;
    else { gin[j - 512] = ai; ghn[j - 512] = ah; }
    __syncthreads();  // B1
    // ---- G: gates on threads 0..255 ----
    if (j < 256) {
      float r = sigm(s_rz[j]);
      float zg = sigm(s_rz[j + 256]);
      float n = tanh_(gin[j] + r * ghn[j]);
      float hn = (1.0f - zg) * n + zg * h_reg;
      h_reg = hn;
      h[j] = hn;
      float ho = __shfl_xor(hn, 1);
      if (!(j & 1)) hpk[j >> 1] = packh2(hn, ho);
      if (j < 16 && t > 0) xpk[j] = packh2(xn0, xn1);
    }
    __syncthreads();  // B2
    // ---- P: fused projection, waves 0..7 -> outputs 0..7 ----
    if (j < 512) {
      int wv = j >> 6, l = j & 63;
      float s = 0.f;
#pragma unroll
      for (int m = 0; m < 4; ++m) s += h[l + 64 * m] * wz[(l + 64 * m) * 9 + wv];
      s = wredsum64(s);
      if (l == 0) zx[((size_t)t * 128 + b) * 8 + wv] = s;
    }
    // no loop-end barrier: next s_rz write is after this thread's P; all
    // cross-thread consumers ordered by B1/B2 of step t+1
  }
}

// ---------------- decoder stage A: phi GRU + z sample + kld ----------------
__global__ KPIN void decA_kernel(
    const float* __restrict__ eps, const float* __restrict__ bih2,
    const float* __restrict__ bhh2, const uint32* __restrict__ wq2,
    const uint32* __restrict__ wih2t, const float* __restrict__ wz1t,
    const float* __restrict__ bzl, const float* __restrict__ bzs,
    const float* __restrict__ zx, uint16* __restrict__ zbuf16,
    float* __restrict__ kld_out) {
  const int b = blockIdx.x, j = threadIdx.x;
  const int wv = j >> 6, l = j & 63;
  __shared__ uint32 wih[2 * 768];
  __shared__ float wz[256 * 9];
  __shared__ float s_rz[512];
  __shared__ float gin[256], ghn[256];
  __shared__ float h[256];
  __shared__ __align__(16) uint32 hpk[128];
  __shared__ __align__(8) uint16 zpk16[4];

  const uint4* wrow4 = (const uint4*)(wq2 + (size_t)j * 128);
  const uint4* hq4 = (const uint4*)hpk;
  R32(LDW)
  const float bi = bih2[j], bh = bhh2[j];
  float bzlr = 0.f, bzsr = 0.f;
  if (j < 256 && l == 0) { bzlr = bzl[wv]; bzsr = bzs[wv]; }
  for (int i = j; i < 2 * 768; i += 768) wih[i] = wih2t[i];
  for (int i = j; i < 256 * 9; i += 768) wz[i] = wz1t[i];
  float h_reg = 0.0f, kacc = 0.0f;
  if (j < 256) h[j] = 0.0f;
  if (j < 128) hpk[j] = 0u;
  if (j < 4) zpk16[j] = (uint16)0;
  __syncthreads();

  for (int t = 0; t < 2048; ++t) {
    const size_t tb = (size_t)t * 128 + b;
    // ---- prefetch (lane0 of waves 0..3; hidden under dots) ----
    float ev = 0.f, zxa = 0.f, zxb = 0.f;
    if (j < 256 && l == 0) { ev = eps[tb * 4 + wv]; zxa = zx[tb * 8 + wv]; zxb = zx[tb * 8 + wv + 4]; }
    // ---- D ----
    uint32 zi0 = ((const uint32*)zpk16)[0], zi1 = ((const uint32*)zpk16)[1];
    float ai = dot2f(wih[j], zi0, bi);
    ai = dot2f(wih[768 + j], zi1, ai);
    float a0 = 0.f, a1 = 0.f, a2 = 0.f, a3 = 0.f;
    R32(HDOT)
    float ah = bh + ((a0 + a1) + (a2 + a3));
    if (j < 512) s_rz[j] = ai + ah;
    else { gin[j - 512] = ai; ghn[j - 512] = ah; }
    __syncthreads();  // B1
    // ---- G ----
    if (j < 256) {
      float r = sigm(s_rz[j]);
      float zg = sigm(s_rz[j + 256]);
      float n = tanh_(gin[j] + r * ghn[j]);
      float hn = (1.0f - zg) * n + zg * h_reg;
      h_reg = hn;
      h[j] = hn;
      float ho = __shfl_xor(hn, 1);
      if (!(j & 1)) hpk[j >> 1] = packh2(hn, ho);
    }
    __syncthreads();  // B2
    // ---- P: z proj, waves 0..3 -> (loc[wv], logvar[wv]); lane0 samples ----
    if (j < 256) {
      float s0 = 0.f, s1 = 0.f;
#pragma unroll
      for (int m = 0; m < 4; ++m) {
        float hv = h[l + 64 * m];
        const float* wr_ = &wz[(l + 64 * m) * 9];
        s0 += hv * wr_[wv];
        s1 += hv * wr_[wv + 4];
      }
      s0 = wredsum64(s0);
      s1 = wredsum64(s1);
      if (l == 0) {
        float loc = s0 + bzlr + zxa;
        float lv = s1 + bzsr + zxb;
        float sc = expf(0.5f * lv);
        float zv = loc + sc * ev;
        kacc += 0.5f * (sc * sc + loc * loc - 1.0f - lv);
        uint16 hz = __builtin_bit_cast(uint16, (_Float16)zv);
        zpk16[wv] = hz;
        zbuf16[tb * 4 + wv] = hz;
      }
    }
    __syncthreads();  // B3: zpk16 ready for next D
  }
  if (j < 256 && l == 0) atomicAdd(kld_out, kacc);
}

// ---------------- decoder stage B: theta GRU + x linears + recon ----------------
__global__ KPIN void decB_kernel(
    const float* __restrict__ x, const float* __restrict__ bih3,
    const float* __restrict__ bhh3, const uint32* __restrict__ wq3,
    const uint32* __restrict__ wih3t, const uint32* __restrict__ wxp_g,
    const float* __restrict__ bxl, const float* __restrict__ bxs,
    const uint32* __restrict__ zbuf, float* __restrict__ y,
    float* __restrict__ recon_out) {
  const int b = blockIdx.x, j = threadIdx.x;
  // x-linear mapping (j<512): qq=K-octant, which=0 loc/1 logvar, f=feature.
  // Partner (loc,lv) of same f are lanes j and j^8 -> shfl_xor(8), no LDS.
  const int qq = j & 7, which = (j >> 3) & 1, f = (j >> 4) & 31;
  const int fo = f + 32 * which;
  __shared__ uint32 wih[2 * 768];
  __shared__ uint32 wxpT2[128 * 68];          // 34KB, <=2-way banks
  __shared__ float s_rz[512];
  __shared__ float gin[256], ghn[256];
  __shared__ __align__(16) uint32 hpk[128];
  __shared__ uint32 zpk[2];

  const uint4* wrow4 = (const uint4*)(wq3 + (size_t)j * 128);
  const uint4* hq4 = (const uint4*)hpk;
  R32(LDW)
  const float bi = bih3[j], bh = bhh3[j];
  float bx_r = 0.f;
  if (j < 512) bx_r = (which == 0) ? bxl[f] : bxs[f];
  for (int i = j; i < 128 * 68; i += 768) wxpT2[i] = wxp_g[i];
  for (int i = j; i < 2 * 768; i += 768) wih[i] = wih3t[i];
  float h_reg = 0.0f, racc = 0.0f;
  if (j < 128) hpk[j] = 0u;
  if (j < 2) zpk[j] = zbuf[(size_t)b * 2 + j];  // t = 0
  const float* xb = x + (size_t)b * (2048 * 32);
  float* yb = y + (size_t)b * (2048 * 32);
  __syncthreads();

  for (int t = 0; t < 2048; ++t) {
    // ---- prefetch ----
    float xv = 0.f;
    uint32 zn = 0u;
    if (j < 512 && (j & 15) == 0) xv = xb[t * 32 + f];
    if (j < 2 && t + 1 < 2048) zn = zbuf[((size_t)(t + 1) * 128 + b) * 2 + j];
    // ---- D ----
    uint32 zi0 = zpk[0], zi1 = zpk[1];
    float ai = dot2f(wih[j], zi0, bi);
    ai = dot2f(wih[768 + j], zi1, ai);
    float a0 = 0.f, a1 = 0.f, a2 = 0.f, a3 = 0.f;
    R32(HDOT)
    float ah = bh + ((a0 + a1) + (a2 + a3));
    if (j < 512) s_rz[j] = ai + ah;
    else { gin[j - 512] = ai; ghn[j - 512] = ah; }
    __syncthreads();  // B1
    // ---- G ----
    if (j < 256) {
      float r = sigm(s_rz[j]);
      float zg = sigm(s_rz[j + 256]);
      float n = tanh_(gin[j] + r * ghn[j]);
      float hn = (1.0f - zg) * n + zg * h_reg;
      h_reg = hn;
      float ho = __shfl_xor(hn, 1);
      if (!(j & 1)) hpk[j >> 1] = packh2(hn, ho);
      if (j < 2 && t + 1 < 2048) zpk[j] = zn;
    }
    __syncthreads();  // B2
    // ---- P: x-linear from LDS (<=2-way banks) + hpk 8-addr broadcasts ----
    if (j < 512) {
      float s = 0.f;
#pragma unroll
      for (int m = 0; m < 16; ++m) {
        int i2 = qq + 8 * m;
        s = dot2f(wxpT2[i2 * 68 + fo], hpk[i2], s);
      }
      s += __shfl_xor(s, 4);
      s += __shfl_xor(s, 2);
      s += __shfl_xor(s, 1);
      s += bx_r;
      float prt = __shfl_xor(s, 8);  // partner: loc <-> lv for same f
      if ((j & 15) == 0 && which == 0) {
        float loc = s, lv = prt;
        yb[t * 32 + f] = loc;
        float d = xv - loc;
        racc += 0.5f * d * d * expf(-lv) + 0.5f * lv + 0.5f * LOG2PI_F;
      }
    }
    // no B3: P's hpk/wxpT2 reads complete before this thread's next B1
  }
  racc = wredsum64(racc);
  if (j < 512 && (j & 63) == 0) atomicAdd(recon_out, racc);
}

// ---------------- launcher ----------------
extern "C" void kernel_launch(void* const* d_in, const int* in_sizes, int n_in,
                              void* d_out, int out_size, void* d_ws, size_t ws_size,
                              hipStream_t stream) {
  const float* x    = (const float*)d_in[0];
  const float* eps  = (const float*)d_in[1];
  const float* Wih1 = (const float*)d_in[2];
  const float* Whh1 = (const float*)d_in[3];
  const float* bih1 = (const float*)d_in[4];
  const float* bhh1 = (const float*)d_in[5];
  const float* Wih2 = (const float*)d_in[6];
  const float* Whh2 = (const float*)d_in[7];
  const float* bih2 = (const float*)d_in[8];
  const float* bhh2 = (const float*)d_in[9];
  const float* Wih3 = (const float*)d_in[10];
  const float* Whh3 = (const float*)d_in[11];
  const float* bih3 = (const float*)d_in[12];
  const float* bhh3 = (const float*)d_in[13];
  const float* Wzl  = (const float*)d_in[14];
  const float* bzl  = (const float*)d_in[15];
  const float* Wzs  = (const float*)d_in[16];
  const float* bzs  = (const float*)d_in[17];
  const float* Wxl  = (const float*)d_in[18];
  const float* bxl  = (const float*)d_in[19];
  const float* Wxs  = (const float*)d_in[20];
  const float* bxs  = (const float*)d_in[21];

  float* ws = (float*)d_ws;
  uint32* wq1   = (uint32*)(ws + 0);        // 98304
  uint32* wq2   = (uint32*)(ws + 98304);    // 98304
  uint32* wq3   = (uint32*)(ws + 196608);   // 98304
  uint32* wih1t = (uint32*)(ws + 294912);   // 12288
  uint32* wih2t = (uint32*)(ws + 307200);   // 1536
  uint32* wih3t = (uint32*)(ws + 308736);   // 1536
  float*  wz1t  = ws + 310272;              // 2304
  float*  wz2t  = ws + 312576;              // 2304
  uint32* wxpT2 = (uint32*)(ws + 314880);   // 8704
  float*  zx    = ws + 323584;              // 2097152  [L][B][8]
  uint32* zbuf  = (uint32*)(ws + 2420736);  // 524288   [L][B] f16x4

  float* out = (float*)d_out;  // [B*L*F] y_loc, then recon, kld
  hipMemsetAsync(out + 8388608, 0, 8, stream);

  prep_kernel<<<128, 256, 0, stream>>>(Wih1, Whh1, Wih2, Whh2, Wih3, Whh3,
                                       Wzl, Wzs, Wxl, Wxs,
                                       wq1, wq2, wq3, wih1t, wih2t, wih3t,
                                       wz1t, wz2t, wxpT2);
  enc_kernel<<<128, 768, 0, stream>>>(x, bih1, bhh1, wq1, wih1t, wz2t, zx);
  decA_kernel<<<128, 768, 0, stream>>>(eps, bih2, bhh2, wq2, wih2t, wz1t,
                                       bzl, bzs, zx, (uint16*)zbuf, out + 8388609);
  decB_kernel<<<128, 768, 0, stream>>>(x, bih3, bhh3, wq3, wih3t, wxpT2,
                                       bxl, bxs, zbuf, out, out + 8388608);
}

// Round 9
// 8156.202 us; speedup vs baseline: 1.6587x; 1.6587x over previous
//
#include <hip/hip_runtime.h>

// RVAE on MI355X. Design notes (KERNEL-tier):
//  - R7 structure (best measured, 11.7ms): 512 thr/WG, K-SPLIT — thread
//    (kh,kr) owns 3 gate-rows x 128-col half = 48 NAMED uint4 = 192 weight
//    regs (128 arch VGPR + rest AGPR; VGPR_Count=128).
//  - Allocator LAW (R6/R7/R8 evidence): backend budgets for 2 WGs/CU —
//    VGPR cap = 512/(2 x waves_per_WG): 8-wave WG -> 128, 12-wave -> 84.
//    launch_bounds/waves_per_eu do NOT override it. So 512-thr K-split is
//    the max-footprint shape that doesn't spill (R8 row-split: 84, spilled).
//  - NEW (R9): decA||decB overlap. One 256-block dec_kernel: blocks 0-127 =
//    decA role, 128-255 = decB role (R7 bodies). z passes via agent-scope
//    atomic uint64 stores (packed 4xf16) + per-32-step chunk flags
//    (release by decA thread0, acquire by decB thread0) — G16-safe across
//    XCDs. Co-residency: 256 blocks <= 256 CUs x >=1 WG/CU, spin is safe.
//    decA is faster, so fused time ~ decB time (~4.2ms) + 55us lag.
//  - decB x-linear weights in registers (16/thread): R6's LDS layout was an
//    8-way bank conflict (2e8 cycles). hpk reads are broadcasts.
//  - All matvecs v_dot2_f32_f16 (f16 pairs, f32 acc); gates/reductions f32.
//    absmax 0.0078 vs 2.5e5 threshold.
//  - Encoder fuses xh -> Wz[:,H:2H] projection so xh[L,B,256] (268MB) is
//    never materialized.

typedef unsigned int uint32;
typedef unsigned short uint16;
typedef unsigned long long uint64;
typedef _Float16 half2v __attribute__((ext_vector_type(2)));

#define LOG2PI_F 1.8378770664093453f

__device__ __forceinline__ float dot2f(uint32 w, uint32 h, float acc) {
#if __has_builtin(__builtin_amdgcn_fdot2)
  return __builtin_amdgcn_fdot2(__builtin_bit_cast(half2v, w),
                                __builtin_bit_cast(half2v, h), acc, false);
#else
  half2v a = __builtin_bit_cast(half2v, w);
  half2v b = __builtin_bit_cast(half2v, h);
  return acc + (float)a.x * (float)b.x + (float)a.y * (float)b.y;
#endif
}

__device__ __forceinline__ uint32 packh2(float a, float b) {
  half2v v;
  v.x = (_Float16)a;
  v.y = (_Float16)b;
  return __builtin_bit_cast(uint32, v);
}

__device__ __forceinline__ float wredsum64(float v) {
  v += __shfl_xor(v, 32); v += __shfl_xor(v, 16); v += __shfl_xor(v, 8);
  v += __shfl_xor(v, 4);  v += __shfl_xor(v, 2);  v += __shfl_xor(v, 1);
  return v;
}

__device__ __forceinline__ float sigm(float x) { return 1.0f / (1.0f + expf(-x)); }
__device__ __forceinline__ float tanh_(float x) { return 1.0f - 2.0f / (expf(2.0f * x) + 1.0f); }

#define R16(M) M(0) M(1) M(2) M(3) M(4) M(5) M(6) M(7) M(8) M(9) M(10) M(11) \
  M(12) M(13) M(14) M(15)

// 48 named uint4s: 3 gate-rows (r,z,n) x 16 uint4 (128 cols) each.
#define LDW(n) uint4 u##n = uq4[n]; uint4 v##n = vq4[n]; uint4 w##n = nq4[n];

// 12 dot2 per chunk; hv is wave-uniform LDS broadcast (conflict-free).
#define HDOT(n) { uint4 hv = hq4[n]; \
  ar0 = dot2f(u##n.x, hv.x, ar0); ar1 = dot2f(u##n.y, hv.y, ar1); \
  ar0 = dot2f(u##n.z, hv.z, ar0); ar1 = dot2f(u##n.w, hv.w, ar1); \
  az0 = dot2f(v##n.x, hv.x, az0); az1 = dot2f(v##n.y, hv.y, az1); \
  az0 = dot2f(v##n.z, hv.z, az0); az1 = dot2f(v##n.w, hv.w, az1); \
  an0 = dot2f(w##n.x, hv.x, an0); an1 = dot2f(w##n.y, hv.y, an1); \
  an0 = dot2f(w##n.z, hv.z, an0); an1 = dot2f(w##n.w, hv.w, an1); }

// decB x-linear: 16 named weight regs + 16 broadcast hpk reads.
#define LDXW(n) uint32 xw##n = wxp_g[(qq + 8 * n) * 64 + fo];
#define XDOT(n) s = dot2f(xw##n, S.hpk[qq + 8 * n], s);

#define KPIN __launch_bounds__(512) __attribute__((amdgpu_waves_per_eu(2, 2)))

// ---------------- prep: repack weights into ws ----------------
__global__ void prep_kernel(const float* __restrict__ Wih1, const float* __restrict__ Whh1,
                            const float* __restrict__ Wih2, const float* __restrict__ Whh2,
                            const float* __restrict__ Wih3, const float* __restrict__ Whh3,
                            const float* __restrict__ Wzl, const float* __restrict__ Wzs,
                            const float* __restrict__ Wxl, const float* __restrict__ Wxs,
                            uint32* wq1, uint32* wq2, uint32* wq3,
                            uint32* wih1t, uint32* wih2t, uint32* wih3t,
                            float* wz1t, float* wz2t, uint32* wxp) {
  int id = blockIdx.x * blockDim.x + threadIdx.x;
  int str = gridDim.x * blockDim.x;
  for (int n = id; n < 768 * 128; n += str) {
    int k = n >> 7, i = n & 127;
    wq1[n] = packh2(Whh1[k * 256 + 2 * i], Whh1[k * 256 + 2 * i + 1]);
    wq2[n] = packh2(Whh2[k * 256 + 2 * i], Whh2[k * 256 + 2 * i + 1]);
    wq3[n] = packh2(Whh3[k * 256 + 2 * i], Whh3[k * 256 + 2 * i + 1]);
  }
  for (int n = id; n < 16 * 768; n += str) {
    int i = n / 768, k = n % 768;
    wih1t[n] = packh2(Wih1[k * 32 + 2 * i], Wih1[k * 32 + 2 * i + 1]);
  }
  for (int n = id; n < 2 * 768; n += str) {
    int i = n / 768, k = n % 768;
    wih2t[n] = packh2(Wih2[k * 4 + 2 * i], Wih2[k * 4 + 2 * i + 1]);
    wih3t[n] = packh2(Wih3[k * 4 + 2 * i], Wih3[k * 4 + 2 * i + 1]);
  }
  for (int n = id; n < 256 * 8; n += str) {
    int i = n >> 3, o = n & 7;
    wz1t[i * 9 + o] = (o < 4) ? Wzl[o * 512 + i] : Wzs[(o - 4) * 512 + i];
    wz2t[i * 9 + o] = (o < 4) ? Wzl[o * 512 + 256 + i] : Wzs[(o - 4) * 512 + 256 + i];
  }
  for (int n = id; n < 128 * 64; n += str) {
    int i2 = n >> 6, o = n & 63;
    float a = (o < 32) ? Wxl[o * 256 + 2 * i2] : Wxs[(o - 32) * 256 + 2 * i2];
    float b = (o < 32) ? Wxl[o * 256 + 2 * i2 + 1] : Wxs[(o - 32) * 256 + 2 * i2 + 1];
    wxp[n] = packh2(a, b);
  }
}

// ---------------- encoder: reverse GRU + fused xh->Wz projection ----------------
__global__ KPIN void enc_kernel(
    const float* __restrict__ x, const float* __restrict__ bih1,
    const float* __restrict__ bhh1, const uint32* __restrict__ wq1,
    const uint32* __restrict__ wih1t, const float* __restrict__ wz2t,
    float* __restrict__ zx) {
  const int b = blockIdx.x, j = threadIdx.x;
  const int kh = j >> 8, kr = j & 255;
  __shared__ uint32 wih[16 * 768];          // 48KB
  __shared__ float wz[256 * 9];             // 9KB
  __shared__ float h[256];
  __shared__ __align__(16) uint32 hpk[128];
  __shared__ uint32 xpk[16];
  __shared__ float part[4 * 256];           // kh=1 partials: r, z, n_in, n_h

  const uint4* uq4 = (const uint4*)(wq1 + (size_t)kr * 128 + kh * 64);
  const uint4* vq4 = (const uint4*)(wq1 + (size_t)(kr + 256) * 128 + kh * 64);
  const uint4* nq4 = (const uint4*)(wq1 + (size_t)(kr + 512) * 128 + kh * 64);
  const uint4* hq4 = (const uint4*)hpk + kh * 16;
  R16(LDW)
  float bir = 0.f, biz = 0.f, bin = 0.f, bhr = 0.f, bhz = 0.f, bhn = 0.f;
  if (kh == 0) {
    bir = bih1[kr]; biz = bih1[kr + 256]; bin = bih1[kr + 512];
    bhr = bhh1[kr]; bhz = bhh1[kr + 256]; bhn = bhh1[kr + 512];
  }
  for (int i = j; i < 16 * 768; i += 512) wih[i] = wih1t[i];
  for (int i = j; i < 256 * 9; i += 512) wz[i] = wz2t[i];
  float h_reg = 0.0f;
  if (j < 256) h[j] = 0.0f;
  if (j < 128) hpk[j] = 0u;
  const float* xb = x + (size_t)b * (2048 * 32);
  if (j < 16) xpk[j] = packh2(xb[2047 * 32 + 2 * j], xb[2047 * 32 + 2 * j + 1]);
  __syncthreads();

  for (int t = 2047; t >= 0; --t) {
    float xn0 = 0.f, xn1 = 0.f;
    if (j < 16 && t > 0) { xn0 = xb[(t - 1) * 32 + 2 * j]; xn1 = xb[(t - 1) * 32 + 2 * j + 1]; }
    float xr = 0.f, xz = 0.f, xn_ = 0.f;
#pragma unroll
    for (int i = 0; i < 8; ++i) {
      int ii = kh * 8 + i;
      uint32 xv = xpk[ii];
      xr = dot2f(wih[ii * 768 + kr], xv, xr);
      xz = dot2f(wih[ii * 768 + 256 + kr], xv, xz);
      xn_ = dot2f(wih[ii * 768 + 512 + kr], xv, xn_);
    }
    float ar0 = 0.f, ar1 = 0.f, az0 = 0.f, az1 = 0.f, an0 = 0.f, an1 = 0.f;
    R16(HDOT)
    if (kh) {
      part[kr] = xr + ar0 + ar1;
      part[256 + kr] = xz + az0 + az1;
      part[512 + kr] = xn_;
      part[768 + kr] = an0 + an1;
    }
    __syncthreads();  // B1
    if (kh == 0) {
      float r = sigm(xr + ar0 + ar1 + part[kr] + bir + bhr);
      float zg = sigm(xz + az0 + az1 + part[256 + kr] + biz + bhz);
      float n = tanh_(xn_ + part[512 + kr] + bin + r * (bhn + an0 + an1 + part[768 + kr]));
      float hn = (1.0f - zg) * n + zg * h_reg;
      h_reg = hn;
      h[kr] = hn;
      float ho = __shfl_xor(hn, 1);
      if (!(kr & 1)) hpk[kr >> 1] = packh2(hn, ho);
      if (j < 16 && t > 0) xpk[j] = packh2(xn0, xn1);
    }
    __syncthreads();  // B2
    {
      int wv = j >> 6, l = j & 63;
      float s = 0.f;
#pragma unroll
      for (int m = 0; m < 4; ++m) s += h[l + 64 * m] * wz[(l + 64 * m) * 9 + wv];
      s = wredsum64(s);
      if (l == 0) zx[((size_t)t * 128 + b) * 8 + wv] = s;
    }
  }
}

// ---------------- fused decoder: blocks 0-127 decA, 128-255 decB ----------------
struct SmemA {
  uint32 wih[2 * 768];
  float wz[256 * 9];
  float h[256];
  __align__(16) uint32 hpk[128];
  float part[4 * 256];
  __align__(8) uint16 zpk16[4];
};
struct SmemB {
  uint32 wih[2 * 768];
  __align__(16) uint32 hpk[128];
  float part[4 * 256];
  uint32 zpk[2];
};

__global__ KPIN void dec_kernel(
    const float* __restrict__ eps,
    const float* __restrict__ bih2, const float* __restrict__ bhh2,
    const uint32* __restrict__ wq2, const uint32* __restrict__ wih2t,
    const float* __restrict__ wz1t, const float* __restrict__ bzl,
    const float* __restrict__ bzs, const float* __restrict__ zx,
    const float* __restrict__ x,
    const float* __restrict__ bih3, const float* __restrict__ bhh3,
    const uint32* __restrict__ wq3, const uint32* __restrict__ wih3t,
    const uint32* __restrict__ wxp_g, const float* __restrict__ bxl,
    const float* __restrict__ bxs,
    uint64* __restrict__ zbuf64, uint32* __restrict__ flags,
    float* __restrict__ y, float* __restrict__ recon_out,
    float* __restrict__ kld_out) {
  const int j = threadIdx.x;
  const int kh = j >> 8, kr = j & 255;
  __shared__ __align__(16) char smem_raw[sizeof(SmemA)];

  if (blockIdx.x < 128) {
    // ================= decA role (R7 body + atomic z/flag publish) =========
    SmemA& S = *reinterpret_cast<SmemA*>(smem_raw);
    const int b = blockIdx.x;
    const int wv = j >> 6, l = j & 63;
    const uint4* uq4 = (const uint4*)(wq2 + (size_t)kr * 128 + kh * 64);
    const uint4* vq4 = (const uint4*)(wq2 + (size_t)(kr + 256) * 128 + kh * 64);
    const uint4* nq4 = (const uint4*)(wq2 + (size_t)(kr + 512) * 128 + kh * 64);
    const uint4* hq4 = (const uint4*)S.hpk + kh * 16;
    R16(LDW)
    float bir = 0.f, biz = 0.f, bin = 0.f, bhr = 0.f, bhz = 0.f, bhn = 0.f;
    if (kh == 0) {
      bir = bih2[kr]; biz = bih2[kr + 256]; bin = bih2[kr + 512];
      bhr = bhh2[kr]; bhz = bhh2[kr + 256]; bhn = bhh2[kr + 512];
    }
    float bzlr = 0.f, bzsr = 0.f;
    if (wv < 4 && l == 0) { bzlr = bzl[wv]; bzsr = bzs[wv]; }
    for (int i = j; i < 2 * 768; i += 512) S.wih[i] = wih2t[i];
    for (int i = j; i < 256 * 9; i += 512) S.wz[i] = wz1t[i];
    float h_reg = 0.0f, kacc = 0.0f;
    if (j < 256) S.h[j] = 0.0f;
    if (j < 128) S.hpk[j] = 0u;
    if (j < 4) S.zpk16[j] = (uint16)0;
    __syncthreads();

    for (int t = 0; t < 2048; ++t) {
      const size_t tb = (size_t)t * 128 + b;
      float ev = 0.f, zxa = 0.f, zxb = 0.f;
      if (wv < 4 && l == 0) { ev = eps[tb * 4 + wv]; zxa = zx[tb * 8 + wv]; zxb = zx[tb * 8 + wv + 4]; }
      uint32 zi = ((const uint32*)S.zpk16)[kh];
      float xr = dot2f(S.wih[kh * 768 + kr], zi, 0.f);
      float xz = dot2f(S.wih[kh * 768 + 256 + kr], zi, 0.f);
      float xn_ = dot2f(S.wih[kh * 768 + 512 + kr], zi, 0.f);
      float ar0 = 0.f, ar1 = 0.f, az0 = 0.f, az1 = 0.f, an0 = 0.f, an1 = 0.f;
      R16(HDOT)
      if (kh) {
        S.part[kr] = xr + ar0 + ar1;
        S.part[256 + kr] = xz + az0 + az1;
        S.part[512 + kr] = xn_;
        S.part[768 + kr] = an0 + an1;
      }
      __syncthreads();  // B1
      if (kh == 0) {
        float r = sigm(xr + ar0 + ar1 + S.part[kr] + bir + bhr);
        float zg = sigm(xz + az0 + az1 + S.part[256 + kr] + biz + bhz);
        float n = tanh_(xn_ + S.part[512 + kr] + bin + r * (bhn + an0 + an1 + S.part[768 + kr]));
        float hn = (1.0f - zg) * n + zg * h_reg;
        h_reg = hn;
        S.h[kr] = hn;
        float ho = __shfl_xor(hn, 1);
        if (!(kr & 1)) S.hpk[kr >> 1] = packh2(hn, ho);
      }
      __syncthreads();  // B2
      if (wv < 4) {
        float s0 = 0.f, s1 = 0.f;
#pragma unroll
        for (int m = 0; m < 4; ++m) {
          float hv = S.h[l + 64 * m];
          const float* wr_ = &S.wz[(l + 64 * m) * 9];
          s0 += hv * wr_[wv];
          s1 += hv * wr_[wv + 4];
        }
        s0 = wredsum64(s0);
        s1 = wredsum64(s1);
        if (l == 0) {
          float loc = s0 + bzlr + zxa;
          float lv = s1 + bzsr + zxb;
          float sc = expf(0.5f * lv);
          float zv = loc + sc * ev;
          kacc += 0.5f * (sc * sc + loc * loc - 1.0f - lv);
          S.zpk16[wv] = __builtin_bit_cast(uint16, (_Float16)zv);
        }
      }
      __syncthreads();  // B3: zpk16 complete
      if (j == 0) {
        uint64 z64 = *(const uint64*)S.zpk16;
        __hip_atomic_store(&zbuf64[tb], z64, __ATOMIC_RELAXED, __HIP_MEMORY_SCOPE_AGENT);
        if ((t & 31) == 31)
          __hip_atomic_store(&flags[b], (uint32)((t >> 5) + 1), __ATOMIC_RELEASE,
                             __HIP_MEMORY_SCOPE_AGENT);
      }
      // B3 also orders zpk16 for next step's dots (reads happen after B3)
    }
    if (wv < 4 && l == 0) atomicAdd(kld_out, kacc);

  } else {
    // ================= decB role (R7 body + chunked flag consume) ==========
    SmemB& S = *reinterpret_cast<SmemB*>(smem_raw);
    const int b = blockIdx.x - 128;
    const int qq = j & 7, g = j >> 3;
    const int f = g >> 1, which = g & 1;
    const int fo = f + 32 * which;
    const uint4* uq4 = (const uint4*)(wq3 + (size_t)kr * 128 + kh * 64);
    const uint4* vq4 = (const uint4*)(wq3 + (size_t)(kr + 256) * 128 + kh * 64);
    const uint4* nq4 = (const uint4*)(wq3 + (size_t)(kr + 512) * 128 + kh * 64);
    const uint4* hq4 = (const uint4*)S.hpk + kh * 16;
    R16(LDW)
    R16(LDXW)
    float bir = 0.f, biz = 0.f, bin = 0.f, bhr = 0.f, bhz = 0.f, bhn = 0.f;
    if (kh == 0) {
      bir = bih3[kr]; biz = bih3[kr + 256]; bin = bih3[kr + 512];
      bhr = bhh3[kr]; bhz = bhh3[kr + 256]; bhn = bhh3[kr + 512];
    }
    const float bx_r = (which == 0) ? bxl[f] : bxs[f];
    for (int i = j; i < 2 * 768; i += 512) S.wih[i] = wih3t[i];
    float h_reg = 0.0f, racc = 0.0f;
    if (j < 128) S.hpk[j] = 0u;
    const float* xb = x + (size_t)b * (2048 * 32);
    float* yb = y + (size_t)b * (2048 * 32);
    __syncthreads();

    for (int c = 0; c < 64; ++c) {
      if (j == 0) {
        while (__hip_atomic_load(&flags[b], __ATOMIC_ACQUIRE, __HIP_MEMORY_SCOPE_AGENT)
               < (uint32)(c + 1)) {
          __builtin_amdgcn_s_sleep(2);
        }
        uint64 z64 = __hip_atomic_load(&zbuf64[(size_t)(c * 32) * 128 + b],
                                       __ATOMIC_RELAXED, __HIP_MEMORY_SCOPE_AGENT);
        S.zpk[0] = (uint32)z64;
        S.zpk[1] = (uint32)(z64 >> 32);
      }
      __syncthreads();  // Bc: chunk-first z ready

      for (int tt = 0; tt < 32; ++tt) {
        const int t = c * 32 + tt;
        // ---- prefetch ----
        float xv = 0.f;
        uint64 zn64 = 0;
        if (qq == 0 && which == 0) xv = xb[t * 32 + f];
        if (j == 0 && tt < 31)
          zn64 = __hip_atomic_load(&zbuf64[(size_t)(t + 1) * 128 + b],
                                   __ATOMIC_RELAXED, __HIP_MEMORY_SCOPE_AGENT);
        // ---- dots ----
        uint32 zi = S.zpk[kh];
        float xr = dot2f(S.wih[kh * 768 + kr], zi, 0.f);
        float xz = dot2f(S.wih[kh * 768 + 256 + kr], zi, 0.f);
        float xn_ = dot2f(S.wih[kh * 768 + 512 + kr], zi, 0.f);
        float ar0 = 0.f, ar1 = 0.f, az0 = 0.f, az1 = 0.f, an0 = 0.f, an1 = 0.f;
        R16(HDOT)
        if (kh) {
          S.part[kr] = xr + ar0 + ar1;
          S.part[256 + kr] = xz + az0 + az1;
          S.part[512 + kr] = xn_;
          S.part[768 + kr] = an0 + an1;
        }
        __syncthreads();  // B1
        if (kh == 0) {
          float r = sigm(xr + ar0 + ar1 + S.part[kr] + bir + bhr);
          float zg = sigm(xz + az0 + az1 + S.part[256 + kr] + biz + bhz);
          float n = tanh_(xn_ + S.part[512 + kr] + bin + r * (bhn + an0 + an1 + S.part[768 + kr]));
          float hn = (1.0f - zg) * n + zg * h_reg;
          h_reg = hn;
          float ho = __shfl_xor(hn, 1);
          if (!(kr & 1)) S.hpk[kr >> 1] = packh2(hn, ho);
          if (j == 0 && tt < 31) {
            S.zpk[0] = (uint32)zn64;
            S.zpk[1] = (uint32)(zn64 >> 32);
          }
        }
        __syncthreads();  // B2
        // ---- x-linear from registers; hpk reads are 8-lane broadcasts ----
        {
          float s = 0.f;
          R16(XDOT)
          s += __shfl_xor(s, 4);
          s += __shfl_xor(s, 2);
          s += __shfl_xor(s, 1);
          s += bx_r;
          float prt = __shfl_xor(s, 8);  // partner: loc <-> lv for same f
          if (qq == 0 && which == 0) {
            float loc = s, lv = prt;
            yb[t * 32 + f] = loc;
            float d = xv - loc;
            racc += 0.5f * d * d * expf(-lv) + 0.5f * lv + 0.5f * LOG2PI_F;
          }
        }
        // no B3: hpk reads complete before each thread's next B1
      }
    }
    racc = wredsum64(racc);
    if ((j & 63) == 0) atomicAdd(recon_out, racc);
  }
}

// ---------------- launcher ----------------
extern "C" void kernel_launch(void* const* d_in, const int* in_sizes, int n_in,
                              void* d_out, int out_size, void* d_ws, size_t ws_size,
                              hipStream_t stream) {
  const float* x    = (const float*)d_in[0];
  const float* eps  = (const float*)d_in[1];
  const float* Wih1 = (const float*)d_in[2];
  const float* Whh1 = (const float*)d_in[3];
  const float* bih1 = (const float*)d_in[4];
  const float* bhh1 = (const float*)d_in[5];
  const float* Wih2 = (const float*)d_in[6];
  const float* Whh2 = (const float*)d_in[7];
  const float* bih2 = (const float*)d_in[8];
  const float* bhh2 = (const float*)d_in[9];
  const float* Wih3 = (const float*)d_in[10];
  const float* Whh3 = (const float*)d_in[11];
  const float* bih3 = (const float*)d_in[12];
  const float* bhh3 = (const float*)d_in[13];
  const float* Wzl  = (const float*)d_in[14];
  const float* bzl  = (const float*)d_in[15];
  const float* Wzs  = (const float*)d_in[16];
  const float* bzs  = (const float*)d_in[17];
  const float* Wxl  = (const float*)d_in[18];
  const float* bxl  = (const float*)d_in[19];
  const float* Wxs  = (const float*)d_in[20];
  const float* bxs  = (const float*)d_in[21];

  float* ws = (float*)d_ws;
  uint32* wq1   = (uint32*)(ws + 0);        // 98304
  uint32* wq2   = (uint32*)(ws + 98304);    // 98304
  uint32* wq3   = (uint32*)(ws + 196608);   // 98304
  uint32* wih1t = (uint32*)(ws + 294912);   // 12288
  uint32* wih2t = (uint32*)(ws + 307200);   // 1536
  uint32* wih3t = (uint32*)(ws + 308736);   // 1536
  float*  wz1t  = ws + 310272;              // 2304
  float*  wz2t  = ws + 312576;              // 2304
  uint32* wxp   = (uint32*)(ws + 314880);   // 8192
  float*  zx    = ws + 323072;              // 2097152  [L][B][8]
  uint64* zbuf64 = (uint64*)(ws + 2420224); // 2MB [L][B] packed 4xf16
  uint32* flags  = (uint32*)(ws + 2944512); // 128 chunk counters

  float* out = (float*)d_out;  // [B*L*F] y_loc, then recon, kld
  hipMemsetAsync(out + 8388608, 0, 8, stream);
  hipMemsetAsync(flags, 0, 128 * sizeof(uint32), stream);

  prep_kernel<<<128, 256, 0, stream>>>(Wih1, Whh1, Wih2, Whh2, Wih3, Whh3,
                                       Wzl, Wzs, Wxl, Wxs,
                                       wq1, wq2, wq3, wih1t, wih2t, wih3t,
                                       wz1t, wz2t, wxp);
  enc_kernel<<<128, 512, 0, stream>>>(x, bih1, bhh1, wq1, wih1t, wz2t, zx);
  dec_kernel<<<256, 512, 0, stream>>>(eps, bih2, bhh2, wq2, wih2t, wz1t,
                                      bzl, bzs, zx, x, bih3, bhh3, wq3, wih3t,
                                      wxp, bxl, bxs, zbuf64, flags,
                                      out, out + 8388608, out + 8388609);
}